// Round 1
// baseline (491.536 us; speedup 1.0000x reference)
//
#include <hip/hip_runtime.h>
#include <stdint.h>

// ---------------------------------------------------------------------------
// Qwen attention block: x@Wqkv -> RMSnorm -> RoPE -> causal GQA flash attn ->
// @Wo.  B=2 T=2048 D=2048 H=16 KH=8 Hd=128.  bf16 MFMA (16x16x32), f32 accum.
// ---------------------------------------------------------------------------

#define B_ 2
#define T_ 2048
#define D_ 2048
#define H_ 16
#define KH_ 8
#define HD_ 128
#define M_ (B_*T_)          // 4096 tokens
#define NQKV_ 4096          // q(2048) | k(1024) | v(1024)
// (1/sqrt(128)) * log2(e): folded into q so softmax uses exp2 directly
#define QK_SCALE_LOG2E 0.1275174337f

typedef unsigned short u16;
typedef unsigned int   u32;
typedef __attribute__((ext_vector_type(8))) __bf16 bf16x8_t;
typedef __attribute__((ext_vector_type(4))) float  f32x4_t;

__device__ __forceinline__ u16 f2bf(float f) {          // RNE f32 -> bf16
    u32 x = __float_as_uint(f);
    return (u16)((x + 0x7fffu + ((x >> 16) & 1u)) >> 16);
}
__device__ __forceinline__ u32 pack2(u16 a, u16 b) { return (u32)a | ((u32)b << 16); }

// async global->LDS, 16B per lane.  LDS dest is wave-uniform base; lane i's
// 16B lands at base + i*16.  Pointer addrspace juggling per CK's pattern
// (generic LDS pointer low 32 bits == LDS offset).
__device__ __forceinline__ void gload16(const void* g, void* l) {
    __builtin_amdgcn_global_load_lds(
        (__attribute__((address_space(1))) const void*)(unsigned long long)g,
        (__attribute__((address_space(3))) void*)(u32)(unsigned long long)l,
        16, 0, 0);
}

// ---------------------------------------------------------------------------
// 1) cast x (f32) -> bf16, 4 elems/thread
// ---------------------------------------------------------------------------
__global__ void cast_x_kernel(const float* __restrict__ in, u16* __restrict__ out) {
    int i = (blockIdx.x * 256 + threadIdx.x) * 4;
    float4 v = *(const float4*)(in + i);
    u32 lo = pack2(f2bf(v.x), f2bf(v.y));
    u32 hi = pack2(f2bf(v.z), f2bf(v.w));
    *(uint2*)(out + i) = make_uint2(lo, hi);
}

// ---------------------------------------------------------------------------
// 2) transpose+cast weight: in f32 [2048][ncols] -> out bf16 [ncols][2048]
// ---------------------------------------------------------------------------
__global__ void tcast_kernel(const float* __restrict__ in, u16* __restrict__ out,
                             int ncols) {
    __shared__ u16 tile[64][65];
    int k0 = blockIdx.x * 64;
    int n0 = blockIdx.y * 64;
    int tid = threadIdx.x;
#pragma unroll
    for (int i = 0; i < 8; ++i) {
        int idx = tid + i * 256;
        int r = idx >> 5, c2 = idx & 31;
        float2 v = *(const float2*)(in + (size_t)(k0 + r) * ncols + n0 + 2 * c2);
        tile[r][2 * c2]     = f2bf(v.x);
        tile[r][2 * c2 + 1] = f2bf(v.y);
    }
    __syncthreads();
#pragma unroll
    for (int i = 0; i < 8; ++i) {
        int idx = tid + i * 256;
        int rn = idx >> 5, c2 = idx & 31;
        *(u32*)(out + (size_t)(n0 + rn) * 2048 + k0 + 2 * c2) =
            pack2(tile[2 * c2][rn], tile[2 * c2 + 1][rn]);
    }
}

// ---------------------------------------------------------------------------
// 3) GEMM: C[M][N] f32 = A[M][2048] bf16 @ Bt[N][2048] bf16 (B transposed).
//    m97 structure: 128x128 tile, BK=32, 4 waves (64x64 each), 16x16x32 MFMA,
//    global_load_lds(16B), XOR chunk swizzle -> 2-way LDS conflicts max.
// ---------------------------------------------------------------------------
__global__ void __launch_bounds__(256)
gemm_kernel(const u16* __restrict__ A, const u16* __restrict__ Bt,
            float* __restrict__ C, int N) {
    __shared__ u16 As[128 * 32];
    __shared__ u16 Bs[128 * 32];
    const int tid  = threadIdx.x;
    const int lane = tid & 63;
    const int wid  = tid >> 6;
    const int m0 = blockIdx.x * 128;
    const int n0 = blockIdx.y * 128;

    // staging: 8 chunks (1024B) per tile per matrix; wave w owns chunks 2w,2w+1
    const int c0 = wid * 2, c1 = wid * 2 + 1;
    const int r0 = c0 * 16 + (lane >> 2);
    const int r1 = c1 * 16 + (lane >> 2);
    const int cl = lane & 3;
    const int g0 = cl ^ ((r0 >> 1) & 3);        // source-side swizzle
    const int g1 = cl ^ ((r1 >> 1) & 3);
    const u16* gA0 = A  + (size_t)(m0 + r0) * 2048 + g0 * 8;
    const u16* gA1 = A  + (size_t)(m0 + r1) * 2048 + g1 * 8;
    const u16* gB0 = Bt + (size_t)(n0 + r0) * 2048 + g0 * 8;
    const u16* gB1 = Bt + (size_t)(n0 + r1) * 2048 + g1 * 8;
    u16* lA0 = As + c0 * 512;
    u16* lA1 = As + c1 * 512;
    u16* lB0 = Bs + c0 * 512;
    u16* lB1 = Bs + c1 * 512;

    const int wm = (wid >> 1) * 64, wn = (wid & 1) * 64;
    const int fr  = lane & 15;   // fragment row / C col
    const int kg  = lane >> 4;   // k-group

    f32x4_t acc[4][4];
#pragma unroll
    for (int m = 0; m < 4; ++m)
#pragma unroll
        for (int n = 0; n < 4; ++n)
#pragma unroll
            for (int j = 0; j < 4; ++j) acc[m][n][j] = 0.0f;

    for (int ks = 0; ks < 64; ++ks) {           // K = 2048 / 32
        gload16(gA0, lA0); gload16(gA1, lA1);
        gload16(gB0, lB0); gload16(gB1, lB1);
        gA0 += 32; gA1 += 32; gB0 += 32; gB1 += 32;
        __syncthreads();                        // drains vmcnt -> tiles ready
        bf16x8_t af[4], bfv[4];
#pragma unroll
        for (int m = 0; m < 4; ++m) {
            int row = wm + m * 16 + fr;
            int phys = kg ^ ((row >> 1) & 3);
            af[m] = *(const bf16x8_t*)(As + row * 32 + phys * 8);
        }
#pragma unroll
        for (int n = 0; n < 4; ++n) {
            int row = wn + n * 16 + fr;
            int phys = kg ^ ((row >> 1) & 3);
            bfv[n] = *(const bf16x8_t*)(Bs + row * 32 + phys * 8);
        }
#pragma unroll
        for (int m = 0; m < 4; ++m)
#pragma unroll
            for (int n = 0; n < 4; ++n)
                acc[m][n] = __builtin_amdgcn_mfma_f32_16x16x32_bf16(
                    af[m], bfv[n], acc[m][n], 0, 0, 0);
        __syncthreads();                        // protect LDS for next stage
    }

    // C/D layout: col = lane&15, row = (lane>>4)*4 + j
#pragma unroll
    for (int m = 0; m < 4; ++m)
#pragma unroll
        for (int n = 0; n < 4; ++n) {
            int col   = n0 + wn + n * 16 + fr;
            int rbase = m0 + wm + m * 16 + kg * 4;
#pragma unroll
            for (int j = 0; j < 4; ++j)
                C[(size_t)(rbase + j) * N + col] = acc[m][n][j];
        }
}

// ---------------------------------------------------------------------------
// 4) RMSnorm + RoPE.  One wave per (token, head-row).  sub: 0..15 q heads,
//    16..23 k heads, 24..31 v heads.  Lane l holds elements 2l,2l+1 = (x1,x2).
// ---------------------------------------------------------------------------
__global__ void __launch_bounds__(256)
normrope_kernel(const float* __restrict__ Cqkv,
                const float* __restrict__ qw, const float* __restrict__ kw,
                const float* __restrict__ sinT, const float* __restrict__ cosT,
                u16* __restrict__ qbf, u16* __restrict__ kbf, u16* __restrict__ vbf) {
    int lane = threadIdx.x & 63;
    int w    = threadIdx.x >> 6;
    int rid  = blockIdx.x * 4 + w;
    int m   = rid >> 5;
    int sub = rid & 31;
    int b = m >> 11, t = m & (T_ - 1);

    if (sub >= 24) {                                     // v: plain cast
        int kh = sub - 24;
        float2 x = *(const float2*)(Cqkv + (size_t)m * NQKV_ + 3072 + kh * HD_ + 2 * lane);
        *(u32*)(vbf + ((size_t)(b * KH_ + kh) * T_ + t) * HD_ + 2 * lane) =
            pack2(f2bf(x.x), f2bf(x.y));
        return;
    }
    bool isq = sub < 16;
    int  hh  = isq ? sub : sub - 16;
    int  colbase = isq ? hh * HD_ : 2048 + hh * HD_;
    float2 x = *(const float2*)(Cqkv + (size_t)m * NQKV_ + colbase + 2 * lane);
    float ss = x.x * x.x + x.y * x.y;
#pragma unroll
    for (int sh = 1; sh < 64; sh <<= 1) ss += __shfl_xor(ss, sh, 64);
    float scale = rsqrtf(ss * (1.0f / 128.0f) + 1e-6f);
    const float* wp = isq ? qw : kw;
    float2 wv = *(const float2*)(wp + 2 * lane);
    float y1 = x.x * scale * wv.x;
    float y2 = x.y * scale * wv.y;
    float c = cosT[t * 64 + lane], s = sinT[t * 64 + lane];
    float oa = y1 * c - y2 * s;              // -> position lane
    float ob = y1 * s + y2 * c;              // -> position 64+lane
    if (isq) { oa *= QK_SCALE_LOG2E; ob *= QK_SCALE_LOG2E; }
    u16* outp = isq ? (qbf + ((size_t)(b * H_  + hh) * T_ + t) * HD_)
                    : (kbf + ((size_t)(b * KH_ + hh) * T_ + t) * HD_);
    outp[lane]      = f2bf(oa);
    outp[64 + lane] = f2bf(ob);
}

// ---------------------------------------------------------------------------
// 5) V transpose: [BH][T][128] -> [BH][128][T]  (64x64 tiles, coalesced both sides)
// ---------------------------------------------------------------------------
__global__ void vtrans_kernel(const u16* __restrict__ in, u16* __restrict__ out) {
    __shared__ u16 tile[64][65];
    int t0 = blockIdx.x * 64;
    int d0 = blockIdx.y * 64;
    size_t bi = (size_t)blockIdx.z * T_ * HD_;
    size_t bo = (size_t)blockIdx.z * HD_ * T_;
    int tid = threadIdx.x;
#pragma unroll
    for (int i = 0; i < 8; ++i) {
        int idx = tid + i * 256;
        int r = idx >> 5, c2 = idx & 31;
        u32 v = *(const u32*)(in + bi + (size_t)(t0 + r) * HD_ + d0 + 2 * c2);
        tile[r][2 * c2]     = (u16)(v & 0xffffu);
        tile[r][2 * c2 + 1] = (u16)(v >> 16);
    }
    __syncthreads();
#pragma unroll
    for (int i = 0; i < 8; ++i) {
        int idx = tid + i * 256;
        int rd = idx >> 5, c2 = idx & 31;
        *(u32*)(out + bo + (size_t)(d0 + rd) * T_ + t0 + 2 * c2) =
            pack2(tile[2 * c2][rd], tile[2 * c2 + 1][rd]);
    }
}

// ---------------------------------------------------------------------------
// 6) Causal GQA flash attention.  Block = 4 waves x 16 q-rows (QBLK=64),
//    KV tile 64.  K tile [64][128] & V^T tile [128][64] staged via
//    swizzled-source global_load_lds; P bounced through padded per-wave LDS.
//    q pre-scaled by 1/sqrt(128)*log2e -> softmax in exp2 space.
// ---------------------------------------------------------------------------
__global__ void __launch_bounds__(256)
attn_kernel(const u16* __restrict__ qg, const u16* __restrict__ kgl,
            const u16* __restrict__ vtg, u16* __restrict__ attout) {
    __shared__ u16 Kt[64 * 128];        // rows = kv, cols = d   (16 KB)
    __shared__ u16 Vt[128 * 64];        // rows = d,  cols = kv  (16 KB)
    __shared__ u16 Pb[4][16 * 72];      // per-wave P, rows padded to 144 B

    const int tid = threadIdx.x, lane = tid & 63, w = tid >> 6;
    const int qb = blockIdx.x, h = blockIdx.y, b = blockIdx.z;
    const int kh = h >> 1;                       // GQA: rep=2
    const int q0 = qb * 64;
    const u16* qbase = qg  + ((size_t)(b * H_  + h ) * T_) * HD_;
    const u16* kbase = kgl + ((size_t)(b * KH_ + kh) * T_) * HD_;
    const u16* vbase = vtg + ((size_t)(b * KH_ + kh) * HD_) * T_;

    const int fr  = lane & 15;
    const int kg4 = lane >> 4;
    const int qw0 = q0 + w * 16;

    // Q fragments (held in registers across all KV tiles)
    bf16x8_t qf[4];
#pragma unroll
    for (int dblk = 0; dblk < 4; ++dblk)
        qf[dblk] = *(const bf16x8_t*)(qbase + (size_t)(qw0 + fr) * HD_ + dblk * 32 + kg4 * 8);

    // staging lane roles
    const int krl = lane >> 4, kcl = lane & 15;   // Kt: 4 rows x 16 chunks / 1KB
    const int vrl = lane >> 3, vcl = lane & 7;    // Vt: 8 rows x 8 chunks / 1KB

    f32x4_t o[8];
#pragma unroll
    for (int dg = 0; dg < 8; ++dg)
#pragma unroll
        for (int j = 0; j < 4; ++j) o[dg][j] = 0.0f;
    float mrow[4], lrow[4];
#pragma unroll
    for (int j = 0; j < 4; ++j) { mrow[j] = -1e30f; lrow[j] = 0.0f; }

    const int nt = qb + 1;
    for (int t = 0; t < nt; ++t) {
        const int kv0 = t * 64;
        // ---- stage K and V^T tiles (8 x 1KB chunks per wave) ----
#pragma unroll
        for (int cc = 0; cc < 4; ++cc) {
            int c = w * 4 + cc;
            int r = c * 4 + krl;
            int g = kcl ^ (r & 7);
            gload16(kbase + (size_t)(kv0 + r) * HD_ + g * 8, Kt + c * 512);
            int rv = c * 8 + vrl;
            int gv = vcl ^ (rv & 7);
            gload16(vbase + (size_t)rv * T_ + kv0 + gv * 8, Vt + c * 512);
        }
        __syncthreads();

        // ---- S = Q K^T (already in log2e*scale space) ----
        f32x4_t s[4];
#pragma unroll
        for (int cg = 0; cg < 4; ++cg) {
#pragma unroll
            for (int j = 0; j < 4; ++j) s[cg][j] = 0.0f;
#pragma unroll
            for (int dblk = 0; dblk < 4; ++dblk) {
                int row  = cg * 16 + fr;
                int phys = (dblk * 4 + kg4) ^ (row & 7);
                bf16x8_t kf = *(const bf16x8_t*)(Kt + row * 128 + phys * 8);
                s[cg] = __builtin_amdgcn_mfma_f32_16x16x32_bf16(qf[dblk], kf, s[cg], 0, 0, 0);
            }
        }
        // ---- causal mask (only the block-diagonal tile) ----
        if (t == nt - 1) {
#pragma unroll
            for (int cg = 0; cg < 4; ++cg) {
                int kv = kv0 + cg * 16 + fr;
#pragma unroll
                for (int j = 0; j < 4; ++j) {
                    int q = qw0 + kg4 * 4 + j;
                    if (kv > q) s[cg][j] = -1e30f;
                }
            }
        }
        // ---- online softmax update ----
        float tm[4];
#pragma unroll
        for (int j = 0; j < 4; ++j)
            tm[j] = fmaxf(fmaxf(s[0][j], s[1][j]), fmaxf(s[2][j], s[3][j]));
#pragma unroll
        for (int sh = 1; sh < 16; sh <<= 1)
#pragma unroll
            for (int j = 0; j < 4; ++j)
                tm[j] = fmaxf(tm[j], __shfl_xor(tm[j], sh, 64));
        float corr[4];
#pragma unroll
        for (int j = 0; j < 4; ++j) {
            float mnew = fmaxf(mrow[j], tm[j]);
            corr[j] = exp2f(mrow[j] - mnew);
            mrow[j] = mnew;
        }
        float pr[4][4], rs[4] = {0.f, 0.f, 0.f, 0.f};
#pragma unroll
        for (int cg = 0; cg < 4; ++cg)
#pragma unroll
            for (int j = 0; j < 4; ++j) {
                float p = exp2f(s[cg][j] - mrow[j]);
                pr[cg][j] = p;
                rs[j] += p;
            }
#pragma unroll
        for (int sh = 1; sh < 16; sh <<= 1)
#pragma unroll
            for (int j = 0; j < 4; ++j) rs[j] += __shfl_xor(rs[j], sh, 64);
#pragma unroll
        for (int j = 0; j < 4; ++j) lrow[j] = lrow[j] * corr[j] + rs[j];
        // rescale O
#pragma unroll
        for (int dg = 0; dg < 8; ++dg)
#pragma unroll
            for (int j = 0; j < 4; ++j) o[dg][j] *= corr[j];
        // ---- P -> per-wave LDS (C-layout write, A-layout read) ----
#pragma unroll
        for (int cg = 0; cg < 4; ++cg)
#pragma unroll
            for (int j = 0; j < 4; ++j)
                Pb[w][(kg4 * 4 + j) * 72 + cg * 16 + fr] = f2bf(pr[cg][j]);
        bf16x8_t pa[2];
#pragma unroll
        for (int kvb = 0; kvb < 2; ++kvb)
            pa[kvb] = *(const bf16x8_t*)(&Pb[w][fr * 72 + kvb * 32 + kg4 * 8]);
        // ---- O += P V ----
#pragma unroll
        for (int dg = 0; dg < 8; ++dg) {
            int d = dg * 16 + fr;
#pragma unroll
            for (int kvb = 0; kvb < 2; ++kvb) {
                int phys = (kvb * 4 + kg4) ^ (d & 7);
                bf16x8_t vf = *(const bf16x8_t*)(Vt + d * 64 + phys * 8);
                o[dg] = __builtin_amdgcn_mfma_f32_16x16x32_bf16(pa[kvb], vf, o[dg], 0, 0, 0);
            }
        }
        __syncthreads();
    }
    // ---- epilogue: O/l -> bf16 att [M][2048] ----
    float inv[4];
#pragma unroll
    for (int j = 0; j < 4; ++j) inv[j] = 1.0f / lrow[j];
    size_t rb = (size_t)(b * T_ + qw0);
#pragma unroll
    for (int dg = 0; dg < 8; ++dg)
#pragma unroll
        for (int j = 0; j < 4; ++j)
            attout[(rb + kg4 * 4 + j) * 2048 + h * HD_ + dg * 16 + fr] =
                f2bf(o[dg][j] * inv[j]);
}

// ---------------------------------------------------------------------------
// launch
// ---------------------------------------------------------------------------
extern "C" void kernel_launch(void* const* d_in, const int* in_sizes, int n_in,
                              void* d_out, int out_size, void* d_ws, size_t ws_size,
                              hipStream_t stream) {
    const float* x    = (const float*)d_in[0];
    const float* Wq   = (const float*)d_in[1];
    const float* Wk   = (const float*)d_in[2];
    const float* Wv   = (const float*)d_in[3];
    const float* Wo   = (const float*)d_in[4];
    const float* qw   = (const float*)d_in[5];
    const float* kw   = (const float*)d_in[6];
    const float* sinT = (const float*)d_in[7];
    const float* cosT = (const float*)d_in[8];
    float* out = (float*)d_out;

    u16*  x_bf   = (u16*)d_ws;                                   // [4096][2048]
    u16*  wqkv_t = x_bf   + (size_t)M_ * D_;                     // [4096][2048]
    u16*  wo_t   = wqkv_t + (size_t)4096 * 2048;                 // [2048][2048]
    float* c_qkv = (float*)(wo_t + (size_t)2048 * 2048);         // [4096][4096]
    u16*  q_bf   = (u16*)(c_qkv + (size_t)M_ * NQKV_);           // [2][16][2048][128]
    u16*  k_bf   = q_bf + (size_t)B_ * H_  * T_ * HD_;           // [2][8][2048][128]
    u16*  v_bf   = k_bf + (size_t)B_ * KH_ * T_ * HD_;           // [2][8][2048][128]
    u16*  v_t    = v_bf + (size_t)B_ * KH_ * T_ * HD_;           // [2][8][128][2048]
    u16*  att_bf = v_t  + (size_t)B_ * KH_ * T_ * HD_;           // [4096][2048]

    cast_x_kernel<<<(M_ * D_) / 1024, 256, 0, stream>>>(x, x_bf);
    tcast_kernel<<<dim3(32, 32), 256, 0, stream>>>(Wq, wqkv_t, 2048);
    tcast_kernel<<<dim3(32, 16), 256, 0, stream>>>(Wk, wqkv_t + (size_t)2048 * 2048, 1024);
    tcast_kernel<<<dim3(32, 16), 256, 0, stream>>>(Wv, wqkv_t + (size_t)3072 * 2048, 1024);
    tcast_kernel<<<dim3(32, 32), 256, 0, stream>>>(Wo, wo_t, 2048);

    gemm_kernel<<<dim3(32, 32), 256, 0, stream>>>(x_bf, wqkv_t, c_qkv, 4096);
    normrope_kernel<<<(M_ * 32) / 4, 256, 0, stream>>>(c_qkv, qw, kw, sinT, cosT,
                                                       q_bf, k_bf, v_bf);
    vtrans_kernel<<<dim3(32, 2, 16), 256, 0, stream>>>(v_bf, v_t);
    attn_kernel<<<dim3(32, 16, 2), 256, 0, stream>>>(q_bf, k_bf, v_t, att_bf);
    gemm_kernel<<<dim3(32, 16), 256, 0, stream>>>(att_bf, wo_t, out, 2048);
}

// Round 2
// 478.154 us; speedup vs baseline: 1.0280x; 1.0280x over previous
//
#include <hip/hip_runtime.h>
#include <stdint.h>

// ---------------------------------------------------------------------------
// Qwen attention block: x@Wqkv -> RMSnorm -> RoPE -> causal GQA flash attn ->
// @Wo.  B=2 T=2048 D=2048 H=16 KH=8 Hd=128.  bf16 MFMA (16x16x32), f32 accum.
// R2: attn rewritten -- QBLK=128 (8 waves), double-buffered K/V staging with
// issue-early prefetch (2-phase template), setprio around MFMA clusters.
// ---------------------------------------------------------------------------

#define B_ 2
#define T_ 2048
#define D_ 2048
#define H_ 16
#define KH_ 8
#define HD_ 128
#define M_ (B_*T_)          // 4096 tokens
#define NQKV_ 4096          // q(2048) | k(1024) | v(1024)
// (1/sqrt(128)) * log2(e): folded into q so softmax uses exp2 directly
#define QK_SCALE_LOG2E 0.1275174337f

typedef unsigned short u16;
typedef unsigned int   u32;
typedef __attribute__((ext_vector_type(8))) __bf16 bf16x8_t;
typedef __attribute__((ext_vector_type(4))) float  f32x4_t;

__device__ __forceinline__ u16 f2bf(float f) {          // RNE f32 -> bf16
    u32 x = __float_as_uint(f);
    return (u16)((x + 0x7fffu + ((x >> 16) & 1u)) >> 16);
}
__device__ __forceinline__ u32 pack2(u16 a, u16 b) { return (u32)a | ((u32)b << 16); }

// async global->LDS, 16B per lane.  LDS dest is wave-uniform base; lane i's
// 16B lands at base + i*16.
__device__ __forceinline__ void gload16(const void* g, void* l) {
    __builtin_amdgcn_global_load_lds(
        (__attribute__((address_space(1))) const void*)(unsigned long long)g,
        (__attribute__((address_space(3))) void*)(u32)(unsigned long long)l,
        16, 0, 0);
}

// ---------------------------------------------------------------------------
// 1) cast x (f32) -> bf16, 4 elems/thread
// ---------------------------------------------------------------------------
__global__ void cast_x_kernel(const float* __restrict__ in, u16* __restrict__ out) {
    int i = (blockIdx.x * 256 + threadIdx.x) * 4;
    float4 v = *(const float4*)(in + i);
    u32 lo = pack2(f2bf(v.x), f2bf(v.y));
    u32 hi = pack2(f2bf(v.z), f2bf(v.w));
    *(uint2*)(out + i) = make_uint2(lo, hi);
}

// ---------------------------------------------------------------------------
// 2) transpose+cast weight: in f32 [2048][ncols] -> out bf16 [ncols][2048]
// ---------------------------------------------------------------------------
__global__ void tcast_kernel(const float* __restrict__ in, u16* __restrict__ out,
                             int ncols) {
    __shared__ u16 tile[64][65];
    int k0 = blockIdx.x * 64;
    int n0 = blockIdx.y * 64;
    int tid = threadIdx.x;
#pragma unroll
    for (int i = 0; i < 8; ++i) {
        int idx = tid + i * 256;
        int r = idx >> 5, c2 = idx & 31;
        float2 v = *(const float2*)(in + (size_t)(k0 + r) * ncols + n0 + 2 * c2);
        tile[r][2 * c2]     = f2bf(v.x);
        tile[r][2 * c2 + 1] = f2bf(v.y);
    }
    __syncthreads();
#pragma unroll
    for (int i = 0; i < 8; ++i) {
        int idx = tid + i * 256;
        int rn = idx >> 5, c2 = idx & 31;
        *(u32*)(out + (size_t)(n0 + rn) * 2048 + k0 + 2 * c2) =
            pack2(tile[2 * c2][rn], tile[2 * c2 + 1][rn]);
    }
}

// ---------------------------------------------------------------------------
// 3) GEMM: C[M][N] f32 = A[M][2048] bf16 @ Bt[N][2048] bf16 (B transposed).
//    m97 structure: 128x128 tile, BK=32, 4 waves (64x64 each), 16x16x32 MFMA,
//    global_load_lds(16B), XOR chunk swizzle -> 2-way LDS conflicts max.
// ---------------------------------------------------------------------------
__global__ void __launch_bounds__(256)
gemm_kernel(const u16* __restrict__ A, const u16* __restrict__ Bt,
            float* __restrict__ C, int N) {
    __shared__ u16 As[128 * 32];
    __shared__ u16 Bs[128 * 32];
    const int tid  = threadIdx.x;
    const int lane = tid & 63;
    const int wid  = tid >> 6;
    const int m0 = blockIdx.x * 128;
    const int n0 = blockIdx.y * 128;

    const int c0 = wid * 2, c1 = wid * 2 + 1;
    const int r0 = c0 * 16 + (lane >> 2);
    const int r1 = c1 * 16 + (lane >> 2);
    const int cl = lane & 3;
    const int g0 = cl ^ ((r0 >> 1) & 3);        // source-side swizzle
    const int g1 = cl ^ ((r1 >> 1) & 3);
    const u16* gA0 = A  + (size_t)(m0 + r0) * 2048 + g0 * 8;
    const u16* gA1 = A  + (size_t)(m0 + r1) * 2048 + g1 * 8;
    const u16* gB0 = Bt + (size_t)(n0 + r0) * 2048 + g0 * 8;
    const u16* gB1 = Bt + (size_t)(n0 + r1) * 2048 + g1 * 8;
    u16* lA0 = As + c0 * 512;
    u16* lA1 = As + c1 * 512;
    u16* lB0 = Bs + c0 * 512;
    u16* lB1 = Bs + c1 * 512;

    const int wm = (wid >> 1) * 64, wn = (wid & 1) * 64;
    const int fr  = lane & 15;
    const int kg  = lane >> 4;

    f32x4_t acc[4][4];
#pragma unroll
    for (int m = 0; m < 4; ++m)
#pragma unroll
        for (int n = 0; n < 4; ++n)
#pragma unroll
            for (int j = 0; j < 4; ++j) acc[m][n][j] = 0.0f;

    for (int ks = 0; ks < 64; ++ks) {           // K = 2048 / 32
        gload16(gA0, lA0); gload16(gA1, lA1);
        gload16(gB0, lB0); gload16(gB1, lB1);
        gA0 += 32; gA1 += 32; gB0 += 32; gB1 += 32;
        __syncthreads();
        bf16x8_t af[4], bfv[4];
#pragma unroll
        for (int m = 0; m < 4; ++m) {
            int row = wm + m * 16 + fr;
            int phys = kg ^ ((row >> 1) & 3);
            af[m] = *(const bf16x8_t*)(As + row * 32 + phys * 8);
        }
#pragma unroll
        for (int n = 0; n < 4; ++n) {
            int row = wn + n * 16 + fr;
            int phys = kg ^ ((row >> 1) & 3);
            bfv[n] = *(const bf16x8_t*)(Bs + row * 32 + phys * 8);
        }
#pragma unroll
        for (int m = 0; m < 4; ++m)
#pragma unroll
            for (int n = 0; n < 4; ++n)
                acc[m][n] = __builtin_amdgcn_mfma_f32_16x16x32_bf16(
                    af[m], bfv[n], acc[m][n], 0, 0, 0);
        __syncthreads();
    }

#pragma unroll
    for (int m = 0; m < 4; ++m)
#pragma unroll
        for (int n = 0; n < 4; ++n) {
            int col   = n0 + wn + n * 16 + fr;
            int rbase = m0 + wm + m * 16 + kg * 4;
#pragma unroll
            for (int j = 0; j < 4; ++j)
                C[(size_t)(rbase + j) * N + col] = acc[m][n][j];
        }
}

// ---------------------------------------------------------------------------
// 4) RMSnorm + RoPE.  One wave per (token, head-row).
// ---------------------------------------------------------------------------
__global__ void __launch_bounds__(256)
normrope_kernel(const float* __restrict__ Cqkv,
                const float* __restrict__ qw, const float* __restrict__ kw,
                const float* __restrict__ sinT, const float* __restrict__ cosT,
                u16* __restrict__ qbf, u16* __restrict__ kbf, u16* __restrict__ vbf) {
    int lane = threadIdx.x & 63;
    int w    = threadIdx.x >> 6;
    int rid  = blockIdx.x * 4 + w;
    int m   = rid >> 5;
    int sub = rid & 31;
    int b = m >> 11, t = m & (T_ - 1);

    if (sub >= 24) {                                     // v: plain cast
        int kh = sub - 24;
        float2 x = *(const float2*)(Cqkv + (size_t)m * NQKV_ + 3072 + kh * HD_ + 2 * lane);
        *(u32*)(vbf + ((size_t)(b * KH_ + kh) * T_ + t) * HD_ + 2 * lane) =
            pack2(f2bf(x.x), f2bf(x.y));
        return;
    }
    bool isq = sub < 16;
    int  hh  = isq ? sub : sub - 16;
    int  colbase = isq ? hh * HD_ : 2048 + hh * HD_;
    float2 x = *(const float2*)(Cqkv + (size_t)m * NQKV_ + colbase + 2 * lane);
    float ss = x.x * x.x + x.y * x.y;
#pragma unroll
    for (int sh = 1; sh < 64; sh <<= 1) ss += __shfl_xor(ss, sh, 64);
    float scale = rsqrtf(ss * (1.0f / 128.0f) + 1e-6f);
    const float* wp = isq ? qw : kw;
    float2 wv = *(const float2*)(wp + 2 * lane);
    float y1 = x.x * scale * wv.x;
    float y2 = x.y * scale * wv.y;
    float c = cosT[t * 64 + lane], s = sinT[t * 64 + lane];
    float oa = y1 * c - y2 * s;
    float ob = y1 * s + y2 * c;
    if (isq) { oa *= QK_SCALE_LOG2E; ob *= QK_SCALE_LOG2E; }
    u16* outp = isq ? (qbf + ((size_t)(b * H_  + hh) * T_ + t) * HD_)
                    : (kbf + ((size_t)(b * KH_ + hh) * T_ + t) * HD_);
    outp[lane]      = f2bf(oa);
    outp[64 + lane] = f2bf(ob);
}

// ---------------------------------------------------------------------------
// 5) V transpose: [BH][T][128] -> [BH][128][T]
// ---------------------------------------------------------------------------
__global__ void vtrans_kernel(const u16* __restrict__ in, u16* __restrict__ out) {
    __shared__ u16 tile[64][65];
    int t0 = blockIdx.x * 64;
    int d0 = blockIdx.y * 64;
    size_t bi = (size_t)blockIdx.z * T_ * HD_;
    size_t bo = (size_t)blockIdx.z * HD_ * T_;
    int tid = threadIdx.x;
#pragma unroll
    for (int i = 0; i < 8; ++i) {
        int idx = tid + i * 256;
        int r = idx >> 5, c2 = idx & 31;
        u32 v = *(const u32*)(in + bi + (size_t)(t0 + r) * HD_ + d0 + 2 * c2);
        tile[r][2 * c2]     = (u16)(v & 0xffffu);
        tile[r][2 * c2 + 1] = (u16)(v >> 16);
    }
    __syncthreads();
#pragma unroll
    for (int i = 0; i < 8; ++i) {
        int idx = tid + i * 256;
        int rd = idx >> 5, c2 = idx & 31;
        *(u32*)(out + bo + (size_t)(d0 + rd) * T_ + t0 + 2 * c2) =
            pack2(tile[2 * c2][rd], tile[2 * c2 + 1][rd]);
    }
}

// ---------------------------------------------------------------------------
// 6) Causal GQA flash attention, R2 structure.
//    Block = 8 waves x 16 q-rows (QBLK=128), KV tile 64, double-buffered
//    K[64][128] / V^T[128][64] staged via swizzled-source global_load_lds.
//    2-phase pipeline: issue STAGE(t+1) before computing tile t; the
//    __syncthreads() at iteration end drains staging AFTER compute covered
//    the latency.  Waves 0-3 stage K, waves 4-7 stage V^T (4 x 1KB each).
//    P bounced through padded per-wave LDS.  q pre-scaled by 1/sqrt(128)*log2e.
// ---------------------------------------------------------------------------
__global__ void __launch_bounds__(512)
attn_kernel(const u16* __restrict__ qg, const u16* __restrict__ kgl,
            const u16* __restrict__ vtg, u16* __restrict__ attout) {
    __shared__ u16 Kt[2][64 * 128];     // rows = kv, cols = d   (16 KB each)
    __shared__ u16 Vt[2][128 * 64];     // rows = d,  cols = kv  (16 KB each)
    __shared__ u16 Pb[8][16 * 72];      // per-wave P, rows padded to 144 B

    const int tid = threadIdx.x, lane = tid & 63, w = tid >> 6;
    const int qb = (int)gridDim.x - 1 - (int)blockIdx.x;   // big blocks first
    const int h = blockIdx.y, b = blockIdx.z;
    const int kh = h >> 1;                       // GQA: rep=2
    const int q0 = qb * 128;
    const u16* qbase = qg  + ((size_t)(b * H_  + h ) * T_) * HD_;
    const u16* kbase = kgl + ((size_t)(b * KH_ + kh) * T_) * HD_;
    const u16* vbase = vtg + ((size_t)(b * KH_ + kh) * HD_) * T_;

    const int fr  = lane & 15;
    const int kg4 = lane >> 4;
    const int qw0 = q0 + w * 16;

    // Q fragments (held in registers across all KV tiles)
    bf16x8_t qf[4];
#pragma unroll
    for (int dblk = 0; dblk < 4; ++dblk)
        qf[dblk] = *(const bf16x8_t*)(qbase + (size_t)(qw0 + fr) * HD_ + dblk * 32 + kg4 * 8);

    // staging lane roles (wave w<4 -> Kt chunks, w>=4 -> Vt chunks; 4 x 1KB per wave)
    const int krl = lane >> 4, kcl = lane & 15;   // Kt chunk: 4 rows x 16 x 16B
    const int vrl = lane >> 3, vcl = lane & 7;    // Vt chunk: 8 rows x  8 x 16B

    f32x4_t o[8];
#pragma unroll
    for (int dg = 0; dg < 8; ++dg)
#pragma unroll
        for (int j = 0; j < 4; ++j) o[dg][j] = 0.0f;
    float mrow[4], lrow[4];
#pragma unroll
    for (int j = 0; j < 4; ++j) { mrow[j] = -1e30f; lrow[j] = 0.0f; }

    const int nt = 2 * (qb + 1);

#define STAGE(buf, tt)                                                         \
    do {                                                                       \
        int kv0s = (tt) * 64;                                                  \
        if (w < 4) {                                                           \
            _Pragma("unroll")                                                  \
            for (int cc = 0; cc < 4; ++cc) {                                   \
                int c = w * 4 + cc;                                            \
                int r = c * 4 + krl;                                           \
                int g = kcl ^ (r & 7);                                         \
                gload16(kbase + (size_t)(kv0s + r) * HD_ + g * 8,              \
                        &Kt[buf][c * 512]);                                    \
            }                                                                  \
        } else {                                                               \
            _Pragma("unroll")                                                  \
            for (int cc = 0; cc < 4; ++cc) {                                   \
                int c = (w - 4) * 4 + cc;                                      \
                int rv = c * 8 + vrl;                                          \
                int gv = vcl ^ (rv & 7);                                       \
                gload16(vbase + (size_t)rv * T_ + kv0s + gv * 8,               \
                        &Vt[buf][c * 512]);                                    \
            }                                                                  \
        }                                                                      \
    } while (0)

    STAGE(0, 0);
    __syncthreads();                    // tile 0 staged

    for (int t = 0; t < nt; ++t) {
        const int cur = t & 1;
        const int kv0 = t * 64;
        if (t + 1 < nt) STAGE(cur ^ 1, t + 1);   // issue-early prefetch

        if (kv0 <= qw0 + 15) {          // wave-uniform: skip tiles above diagonal
            // ---- S = Q K^T (already in log2e*scale space) ----
            f32x4_t s[4];
            __builtin_amdgcn_s_setprio(1);
#pragma unroll
            for (int cg = 0; cg < 4; ++cg) {
#pragma unroll
                for (int j = 0; j < 4; ++j) s[cg][j] = 0.0f;
#pragma unroll
                for (int dblk = 0; dblk < 4; ++dblk) {
                    int row  = cg * 16 + fr;
                    int phys = (dblk * 4 + kg4) ^ (row & 7);
                    bf16x8_t kf = *(const bf16x8_t*)(&Kt[cur][row * 128 + phys * 8]);
                    s[cg] = __builtin_amdgcn_mfma_f32_16x16x32_bf16(qf[dblk], kf, s[cg], 0, 0, 0);
                }
            }
            __builtin_amdgcn_s_setprio(0);
            // ---- causal mask (diagonal tiles only) ----
            if (kv0 + 63 > qw0) {
#pragma unroll
                for (int cg = 0; cg < 4; ++cg) {
                    int kv = kv0 + cg * 16 + fr;
#pragma unroll
                    for (int j = 0; j < 4; ++j) {
                        int q = qw0 + kg4 * 4 + j;
                        if (kv > q) s[cg][j] = -1e30f;
                    }
                }
            }
            // ---- online softmax update ----
            float tm[4];
#pragma unroll
            for (int j = 0; j < 4; ++j)
                tm[j] = fmaxf(fmaxf(s[0][j], s[1][j]), fmaxf(s[2][j], s[3][j]));
#pragma unroll
            for (int sh = 1; sh < 16; sh <<= 1)
#pragma unroll
                for (int j = 0; j < 4; ++j)
                    tm[j] = fmaxf(tm[j], __shfl_xor(tm[j], sh, 64));
            float corr[4];
#pragma unroll
            for (int j = 0; j < 4; ++j) {
                float mnew = fmaxf(mrow[j], tm[j]);
                corr[j] = exp2f(mrow[j] - mnew);
                mrow[j] = mnew;
            }
            float pr[4][4], rs[4] = {0.f, 0.f, 0.f, 0.f};
#pragma unroll
            for (int cg = 0; cg < 4; ++cg)
#pragma unroll
                for (int j = 0; j < 4; ++j) {
                    float p = exp2f(s[cg][j] - mrow[j]);
                    pr[cg][j] = p;
                    rs[j] += p;
                }
#pragma unroll
            for (int sh = 1; sh < 16; sh <<= 1)
#pragma unroll
                for (int j = 0; j < 4; ++j) rs[j] += __shfl_xor(rs[j], sh, 64);
#pragma unroll
            for (int j = 0; j < 4; ++j) lrow[j] = lrow[j] * corr[j] + rs[j];
#pragma unroll
            for (int dg = 0; dg < 8; ++dg)
#pragma unroll
                for (int j = 0; j < 4; ++j) o[dg][j] *= corr[j];
            // ---- P -> per-wave LDS (C-layout write, A-layout read) ----
#pragma unroll
            for (int cg = 0; cg < 4; ++cg)
#pragma unroll
                for (int j = 0; j < 4; ++j)
                    Pb[w][(kg4 * 4 + j) * 72 + cg * 16 + fr] = f2bf(pr[cg][j]);
            bf16x8_t pa[2];
#pragma unroll
            for (int kvb = 0; kvb < 2; ++kvb)
                pa[kvb] = *(const bf16x8_t*)(&Pb[w][fr * 72 + kvb * 32 + kg4 * 8]);
            // ---- O += P V ----
            __builtin_amdgcn_s_setprio(1);
#pragma unroll
            for (int dg = 0; dg < 8; ++dg) {
                int d = dg * 16 + fr;
#pragma unroll
                for (int kvb = 0; kvb < 2; ++kvb) {
                    int phys = (kvb * 4 + kg4) ^ (d & 7);
                    bf16x8_t vf = *(const bf16x8_t*)(&Vt[cur][d * 64 + phys * 8]);
                    o[dg] = __builtin_amdgcn_mfma_f32_16x16x32_bf16(pa[kvb], vf, o[dg], 0, 0, 0);
                }
            }
            __builtin_amdgcn_s_setprio(0);
        }
        __syncthreads();                // drains prefetch (hidden) + LDS reuse
    }
#undef STAGE

    // ---- epilogue: O/l -> bf16 att [M][2048] ----
    float inv[4];
#pragma unroll
    for (int j = 0; j < 4; ++j) inv[j] = 1.0f / lrow[j];
    size_t rb = (size_t)(b * T_ + qw0);
#pragma unroll
    for (int dg = 0; dg < 8; ++dg)
#pragma unroll
        for (int j = 0; j < 4; ++j)
            attout[(rb + kg4 * 4 + j) * 2048 + h * HD_ + dg * 16 + fr] =
                f2bf(o[dg][j] * inv[j]);
}

// ---------------------------------------------------------------------------
// launch
// ---------------------------------------------------------------------------
extern "C" void kernel_launch(void* const* d_in, const int* in_sizes, int n_in,
                              void* d_out, int out_size, void* d_ws, size_t ws_size,
                              hipStream_t stream) {
    const float* x    = (const float*)d_in[0];
    const float* Wq   = (const float*)d_in[1];
    const float* Wk   = (const float*)d_in[2];
    const float* Wv   = (const float*)d_in[3];
    const float* Wo   = (const float*)d_in[4];
    const float* qw   = (const float*)d_in[5];
    const float* kw   = (const float*)d_in[6];
    const float* sinT = (const float*)d_in[7];
    const float* cosT = (const float*)d_in[8];
    float* out = (float*)d_out;

    u16*  x_bf   = (u16*)d_ws;                                   // [4096][2048]
    u16*  wqkv_t = x_bf   + (size_t)M_ * D_;                     // [4096][2048]
    u16*  wo_t   = wqkv_t + (size_t)4096 * 2048;                 // [2048][2048]
    float* c_qkv = (float*)(wo_t + (size_t)2048 * 2048);         // [4096][4096]
    u16*  q_bf   = (u16*)(c_qkv + (size_t)M_ * NQKV_);           // [2][16][2048][128]
    u16*  k_bf   = q_bf + (size_t)B_ * H_  * T_ * HD_;           // [2][8][2048][128]
    u16*  v_bf   = k_bf + (size_t)B_ * KH_ * T_ * HD_;           // [2][8][2048][128]
    u16*  v_t    = v_bf + (size_t)B_ * KH_ * T_ * HD_;           // [2][8][128][2048]
    u16*  att_bf = v_t  + (size_t)B_ * KH_ * T_ * HD_;           // [4096][2048]

    cast_x_kernel<<<(M_ * D_) / 1024, 256, 0, stream>>>(x, x_bf);
    tcast_kernel<<<dim3(32, 32), 256, 0, stream>>>(Wq, wqkv_t, 2048);
    tcast_kernel<<<dim3(32, 16), 256, 0, stream>>>(Wk, wqkv_t + (size_t)2048 * 2048, 1024);
    tcast_kernel<<<dim3(32, 16), 256, 0, stream>>>(Wv, wqkv_t + (size_t)3072 * 2048, 1024);
    tcast_kernel<<<dim3(32, 32), 256, 0, stream>>>(Wo, wo_t, 2048);

    gemm_kernel<<<dim3(32, 32), 256, 0, stream>>>(x_bf, wqkv_t, c_qkv, 4096);
    normrope_kernel<<<(M_ * 32) / 4, 256, 0, stream>>>(c_qkv, qw, kw, sinT, cosT,
                                                       q_bf, k_bf, v_bf);
    vtrans_kernel<<<dim3(32, 2, 16), 256, 0, stream>>>(v_bf, v_t);
    attn_kernel<<<dim3(16, 16, 2), 512, 0, stream>>>(q_bf, k_bf, v_t, att_bf);
    gemm_kernel<<<dim3(32, 16), 256, 0, stream>>>(att_bf, wo_t, out, 2048);
}

// Round 5
// 415.040 us; speedup vs baseline: 1.1843x; 1.1521x over previous
//
#include <hip/hip_runtime.h>
#include <stdint.h>

// ---------------------------------------------------------------------------
// Qwen attention block: x@Wqkv -> RMSnorm -> RoPE -> causal GQA flash attn ->
// @Wo.  B=2 T=2048 D=2048 H=16 KH=8 Hd=128.  bf16 MFMA, f32 accum.
// R5 (= R4 resubmit, bench infra failed twice): attn in m214/HK style --
// 32x32x16 MFMA, swapped QK^T (S^T = mfma(K,Q)) and swapped PV
// (O^T = mfma(V^T,P)) so softmax state is lane-local; in-register P
// redistribution via shfl_xor(32); XOR-swizzled K/V^T LDS tiles (K slot
// swizzle 4-bit); double-buffered issue-early staging; packed b64 epilogue.
// ---------------------------------------------------------------------------

#define B_ 2
#define T_ 2048
#define D_ 2048
#define H_ 16
#define KH_ 8
#define HD_ 128
#define M_ (B_*T_)          // 4096 tokens
#define NQKV_ 4096          // q(2048) | k(1024) | v(1024)
// (1/sqrt(128)) * log2(e): folded into q so softmax uses exp2 directly
#define QK_SCALE_LOG2E 0.1275174337f

typedef unsigned short u16;
typedef unsigned int   u32;
typedef __attribute__((ext_vector_type(8)))  __bf16 bf16x8_t;
typedef __attribute__((ext_vector_type(4)))  float  f32x4_t;
typedef __attribute__((ext_vector_type(16))) float  f32x16_t;
typedef __attribute__((ext_vector_type(4)))  u32    u32x4_t;

__device__ __forceinline__ u16 f2bf(float f) {          // RNE f32 -> bf16
    u32 x = __float_as_uint(f);
    return (u16)((x + 0x7fffu + ((x >> 16) & 1u)) >> 16);
}
__device__ __forceinline__ u32 pack2(u16 a, u16 b) { return (u32)a | ((u32)b << 16); }

// async global->LDS, 16B per lane.  LDS dest is wave-uniform base; lane i's
// 16B lands at base + i*16.
__device__ __forceinline__ void gload16(const void* g, void* l) {
    __builtin_amdgcn_global_load_lds(
        (__attribute__((address_space(1))) const void*)(unsigned long long)g,
        (__attribute__((address_space(3))) void*)(u32)(unsigned long long)l,
        16, 0, 0);
}

// ---------------------------------------------------------------------------
// 1) cast x (f32) -> bf16, 4 elems/thread
// ---------------------------------------------------------------------------
__global__ void cast_x_kernel(const float* __restrict__ in, u16* __restrict__ out) {
    int i = (blockIdx.x * 256 + threadIdx.x) * 4;
    float4 v = *(const float4*)(in + i);
    u32 lo = pack2(f2bf(v.x), f2bf(v.y));
    u32 hi = pack2(f2bf(v.z), f2bf(v.w));
    *(uint2*)(out + i) = make_uint2(lo, hi);
}

// ---------------------------------------------------------------------------
// 2) transpose+cast weight: in f32 [2048][ncols] -> out bf16 [ncols][2048]
// ---------------------------------------------------------------------------
__global__ void tcast_kernel(const float* __restrict__ in, u16* __restrict__ out,
                             int ncols) {
    __shared__ u16 tile[64][65];
    int k0 = blockIdx.x * 64;
    int n0 = blockIdx.y * 64;
    int tid = threadIdx.x;
#pragma unroll
    for (int i = 0; i < 8; ++i) {
        int idx = tid + i * 256;
        int r = idx >> 5, c2 = idx & 31;
        float2 v = *(const float2*)(in + (size_t)(k0 + r) * ncols + n0 + 2 * c2);
        tile[r][2 * c2]     = f2bf(v.x);
        tile[r][2 * c2 + 1] = f2bf(v.y);
    }
    __syncthreads();
#pragma unroll
    for (int i = 0; i < 8; ++i) {
        int idx = tid + i * 256;
        int rn = idx >> 5, c2 = idx & 31;
        *(u32*)(out + (size_t)(n0 + rn) * 2048 + k0 + 2 * c2) =
            pack2(tile[2 * c2][rn], tile[2 * c2 + 1][rn]);
    }
}

// ---------------------------------------------------------------------------
// 3) GEMM: C[M][N] f32 = A[M][2048] bf16 @ Bt[N][2048] bf16 (B transposed).
//    m97 structure (frozen for clean attn A/B).
// ---------------------------------------------------------------------------
__global__ void __launch_bounds__(256)
gemm_kernel(const u16* __restrict__ A, const u16* __restrict__ Bt,
            float* __restrict__ C, int N) {
    __shared__ u16 As[128 * 32];
    __shared__ u16 Bs[128 * 32];
    const int tid  = threadIdx.x;
    const int lane = tid & 63;
    const int wid  = tid >> 6;
    const int m0 = blockIdx.x * 128;
    const int n0 = blockIdx.y * 128;

    const int c0 = wid * 2, c1 = wid * 2 + 1;
    const int r0 = c0 * 16 + (lane >> 2);
    const int r1 = c1 * 16 + (lane >> 2);
    const int cl = lane & 3;
    const int g0 = cl ^ ((r0 >> 1) & 3);
    const int g1 = cl ^ ((r1 >> 1) & 3);
    const u16* gA0 = A  + (size_t)(m0 + r0) * 2048 + g0 * 8;
    const u16* gA1 = A  + (size_t)(m0 + r1) * 2048 + g1 * 8;
    const u16* gB0 = Bt + (size_t)(n0 + r0) * 2048 + g0 * 8;
    const u16* gB1 = Bt + (size_t)(n0 + r1) * 2048 + g1 * 8;
    u16* lA0 = As + c0 * 512;
    u16* lA1 = As + c1 * 512;
    u16* lB0 = Bs + c0 * 512;
    u16* lB1 = Bs + c1 * 512;

    const int wm = (wid >> 1) * 64, wn = (wid & 1) * 64;
    const int fr  = lane & 15;
    const int kg  = lane >> 4;

    f32x4_t acc[4][4];
#pragma unroll
    for (int m = 0; m < 4; ++m)
#pragma unroll
        for (int n = 0; n < 4; ++n)
#pragma unroll
            for (int j = 0; j < 4; ++j) acc[m][n][j] = 0.0f;

    for (int ks = 0; ks < 64; ++ks) {
        gload16(gA0, lA0); gload16(gA1, lA1);
        gload16(gB0, lB0); gload16(gB1, lB1);
        gA0 += 32; gA1 += 32; gB0 += 32; gB1 += 32;
        __syncthreads();
        bf16x8_t af[4], bfv[4];
#pragma unroll
        for (int m = 0; m < 4; ++m) {
            int row = wm + m * 16 + fr;
            int phys = kg ^ ((row >> 1) & 3);
            af[m] = *(const bf16x8_t*)(As + row * 32 + phys * 8);
        }
#pragma unroll
        for (int n = 0; n < 4; ++n) {
            int row = wn + n * 16 + fr;
            int phys = kg ^ ((row >> 1) & 3);
            bfv[n] = *(const bf16x8_t*)(Bs + row * 32 + phys * 8);
        }
#pragma unroll
        for (int m = 0; m < 4; ++m)
#pragma unroll
            for (int n = 0; n < 4; ++n)
                acc[m][n] = __builtin_amdgcn_mfma_f32_16x16x32_bf16(
                    af[m], bfv[n], acc[m][n], 0, 0, 0);
        __syncthreads();
    }

#pragma unroll
    for (int m = 0; m < 4; ++m)
#pragma unroll
        for (int n = 0; n < 4; ++n) {
            int col   = n0 + wn + n * 16 + fr;
            int rbase = m0 + wm + m * 16 + kg * 4;
#pragma unroll
            for (int j = 0; j < 4; ++j)
                C[(size_t)(rbase + j) * N + col] = acc[m][n][j];
        }
}

// ---------------------------------------------------------------------------
// 4) RMSnorm + RoPE.  One wave per (token, head-row).
// ---------------------------------------------------------------------------
__global__ void __launch_bounds__(256)
normrope_kernel(const float* __restrict__ Cqkv,
                const float* __restrict__ qw, const float* __restrict__ kw,
                const float* __restrict__ sinT, const float* __restrict__ cosT,
                u16* __restrict__ qbf, u16* __restrict__ kbf, u16* __restrict__ vbf) {
    int lane = threadIdx.x & 63;
    int w    = threadIdx.x >> 6;
    int rid  = blockIdx.x * 4 + w;
    int m   = rid >> 5;
    int sub = rid & 31;
    int b = m >> 11, t = m & (T_ - 1);

    if (sub >= 24) {                                     // v: plain cast
        int kh = sub - 24;
        float2 x = *(const float2*)(Cqkv + (size_t)m * NQKV_ + 3072 + kh * HD_ + 2 * lane);
        *(u32*)(vbf + ((size_t)(b * KH_ + kh) * T_ + t) * HD_ + 2 * lane) =
            pack2(f2bf(x.x), f2bf(x.y));
        return;
    }
    bool isq = sub < 16;
    int  hh  = isq ? sub : sub - 16;
    int  colbase = isq ? hh * HD_ : 2048 + hh * HD_;
    float2 x = *(const float2*)(Cqkv + (size_t)m * NQKV_ + colbase + 2 * lane);
    float ss = x.x * x.x + x.y * x.y;
#pragma unroll
    for (int sh = 1; sh < 64; sh <<= 1) ss += __shfl_xor(ss, sh, 64);
    float scale = rsqrtf(ss * (1.0f / 128.0f) + 1e-6f);
    const float* wp = isq ? qw : kw;
    float2 wv = *(const float2*)(wp + 2 * lane);
    float y1 = x.x * scale * wv.x;
    float y2 = x.y * scale * wv.y;
    float c = cosT[t * 64 + lane], s = sinT[t * 64 + lane];
    float oa = y1 * c - y2 * s;
    float ob = y1 * s + y2 * c;
    if (isq) { oa *= QK_SCALE_LOG2E; ob *= QK_SCALE_LOG2E; }
    u16* outp = isq ? (qbf + ((size_t)(b * H_  + hh) * T_ + t) * HD_)
                    : (kbf + ((size_t)(b * KH_ + hh) * T_ + t) * HD_);
    outp[lane]      = f2bf(oa);
    outp[64 + lane] = f2bf(ob);
}

// ---------------------------------------------------------------------------
// 5) V transpose: [BH][T][128] -> [BH][128][T]
// ---------------------------------------------------------------------------
__global__ void vtrans_kernel(const u16* __restrict__ in, u16* __restrict__ out) {
    __shared__ u16 tile[64][65];
    int t0 = blockIdx.x * 64;
    int d0 = blockIdx.y * 64;
    size_t bi = (size_t)blockIdx.z * T_ * HD_;
    size_t bo = (size_t)blockIdx.z * HD_ * T_;
    int tid = threadIdx.x;
#pragma unroll
    for (int i = 0; i < 8; ++i) {
        int idx = tid + i * 256;
        int r = idx >> 5, c2 = idx & 31;
        u32 v = *(const u32*)(in + bi + (size_t)(t0 + r) * HD_ + d0 + 2 * c2);
        tile[r][2 * c2]     = (u16)(v & 0xffffu);
        tile[r][2 * c2 + 1] = (u16)(v >> 16);
    }
    __syncthreads();
#pragma unroll
    for (int i = 0; i < 8; ++i) {
        int idx = tid + i * 256;
        int rd = idx >> 5, c2 = idx & 31;
        *(u32*)(out + bo + (size_t)(d0 + rd) * T_ + t0 + 2 * c2) =
            pack2(tile[2 * c2][rd], tile[2 * c2 + 1][rd]);
    }
}

// ---------------------------------------------------------------------------
// 6) Causal GQA flash attention, R3/R4 structure.
//    4 waves x 32 q-rows (QBLK=128); KV tile 64, double-buffered.
//    S^T = mfma_32x32x16(A=K, B=Q)  -> lane owns q-col (col=lane&31):
//      softmax m/l/corr fully lane-local (one shfl_xor(32) per tile).
//    O^T = mfma_32x32x16(A=V^T, B=P) -> same q-col mapping, so the corr
//      rescale is lane-local too.  P redistributed in-register (shfl_xor 32).
//    K LDS [64][16 slots] with 4-bit XOR slot swizzle (2-way max on reads);
//    V^T LDS [128][8 slots] with 3-bit swizzle.  Both staged via
//    pre-swizzled-source global_load_lds (rule #21: swizzle both sides).
// ---------------------------------------------------------------------------
__global__ void __launch_bounds__(256, 2)
attn_kernel(const u16* __restrict__ qg, const u16* __restrict__ kgl,
            const u16* __restrict__ vtg, u16* __restrict__ attout) {
    __shared__ u16 Kt[2][64 * 128];     // 16 KB each: rows = kv, 16 slots of 16B
    __shared__ u16 Vt[2][128 * 64];     // 16 KB each: rows = d,   8 slots of 16B

    const int tid = threadIdx.x, lane = tid & 63, w = tid >> 6;
    const int qb = (int)gridDim.x - 1 - (int)blockIdx.x;   // big blocks first
    const int h = blockIdx.y, b = blockIdx.z;
    const int kh = h >> 1;                       // GQA rep=2
    const int q0 = qb * 128;
    const int col = lane & 31;                   // q index within wave tile
    const int hi  = lane >> 5;                   // half selector
    const int l7  = lane & 7;
    const int l15 = lane & 15;
    const int qw0 = q0 + w * 32;
    const int qlane = qw0 + col;                 // this lane's q row

    const u16* qbase = qg  + ((size_t)(b * H_  + h ) * T_) * HD_;
    const u16* kbase = kgl + ((size_t)(b * KH_ + kh) * T_) * HD_;
    const u16* vbase = vtg + ((size_t)(b * KH_ + kh) * HD_) * T_;

    // Q as B-operand fragments: qf[s] = Q[qlane][s*16 + 8*hi + j], j=0..7
    bf16x8_t qf[8];
#pragma unroll
    for (int s = 0; s < 8; ++s)
        qf[s] = *(const bf16x8_t*)(qbase + (size_t)qlane * HD_ + s * 16 + hi * 8);

    // staging lane roles
    const int krl = lane >> 4, kcl = lane & 15;   // K chunk: 4 rows x 16 slots
    const int vrl = lane >> 3, vcl = lane & 7;    // V chunk: 8 rows x 8 slots

    f32x16_t o[4];                               // O^T: d = dt*32+crow, q = col
#pragma unroll
    for (int dt = 0; dt < 4; ++dt)
#pragma unroll
        for (int r = 0; r < 16; ++r) o[dt][r] = 0.0f;
    float mrow = -1e30f, lrow = 0.0f;            // lrow = PARTIAL (own 32 kv/tile)

    const int nt = 2 * (qb + 1);

#define STAGE(buf, tt)                                                          \
    do {                                                                        \
        int kv0s = (tt) * 64;                                                   \
        _Pragma("unroll")                                                       \
        for (int cc = 0; cc < 4; ++cc) {                                        \
            int c = w * 4 + cc;                                                 \
            int r = c * 4 + krl;                                                \
            gload16(kbase + (size_t)(kv0s + r) * HD_ + (kcl ^ (r & 15)) * 8,    \
                    &Kt[buf][c * 512]);                                         \
            int rv = c * 8 + vrl;                                               \
            gload16(vbase + (size_t)rv * T_ + kv0s + (vcl ^ (rv & 7)) * 8,      \
                    &Vt[buf][c * 512]);                                         \
        }                                                                       \
    } while (0)

    STAGE(0, 0);
    __syncthreads();                    // tile 0 staged

    for (int t = 0; t < nt; ++t) {
        const int cur = t & 1;
        const int kv0 = t * 64;
        if (t + 1 < nt) STAGE(cur ^ 1, t + 1);   // issue-early prefetch

        if (kv0 <= qw0 + 31) {          // wave-uniform diagonal skip
            // ---- S^T = K Q^T: A=K[kv][d], B=Q[d][q] (pre-scaled log2e) ----
            f32x16_t s0, s1;
#pragma unroll
            for (int r = 0; r < 16; ++r) { s0[r] = 0.0f; s1[r] = 0.0f; }
            __builtin_amdgcn_s_setprio(1);
#pragma unroll
            for (int ss = 0; ss < 8; ++ss) {
                bf16x8_t kf0 = *(const bf16x8_t*)
                    (&Kt[cur][col * 128 + (((2 * ss + hi) ^ l15) * 8)]);
                s0 = __builtin_amdgcn_mfma_f32_32x32x16_bf16(kf0, qf[ss], s0, 0, 0, 0);
                bf16x8_t kf1 = *(const bf16x8_t*)
                    (&Kt[cur][(32 + col) * 128 + (((2 * ss + hi) ^ l15) * 8)]);
                s1 = __builtin_amdgcn_mfma_f32_32x32x16_bf16(kf1, qf[ss], s1, 0, 0, 0);
            }
            __builtin_amdgcn_s_setprio(0);
            // ---- causal mask (tiles overlapping any of this wave's rows) ----
            if (kv0 + 63 > qw0) {
#pragma unroll
                for (int r = 0; r < 16; ++r) {
                    int cr = (r & 3) + 8 * (r >> 2) + 4 * hi;
                    if (kv0 + cr      > qlane) s0[r] = -1e30f;
                    if (kv0 + 32 + cr > qlane) s1[r] = -1e30f;
                }
            }
            // ---- softmax (lane-local; one cross-half combine for max) ----
            float tmax = s0[0];
#pragma unroll
            for (int r = 1; r < 16; ++r) tmax = fmaxf(tmax, s0[r]);
#pragma unroll
            for (int r = 0; r < 16; ++r) tmax = fmaxf(tmax, s1[r]);
            tmax = fmaxf(tmax, __shfl_xor(tmax, 32, 64));
            float mnew = fmaxf(mrow, tmax);
            float corr = exp2f(mrow - mnew);
            mrow = mnew;
            float ps = 0.0f;
#pragma unroll
            for (int r = 0; r < 16; ++r) {
                s0[r] = exp2f(s0[r] - mrow); ps += s0[r];
                s1[r] = exp2f(s1[r] - mrow); ps += s1[r];
            }
            lrow = lrow * corr + ps;            // stays partial per half-lane
#pragma unroll
            for (int dt = 0; dt < 4; ++dt)
#pragma unroll
                for (int r = 0; r < 16; ++r) o[dt][r] *= corr;
            // ---- P -> bf16 pairs, redistribute to B-operand layout ----
            // reg r holds kv' = (r&3)+8*(r>>2)+4*hi (within its 32-subtile).
            u32 pd0[8], pd1[8], po0[8], po1[8];
#pragma unroll
            for (int i = 0; i < 8; ++i) {
                pd0[i] = pack2(f2bf(s0[2 * i]), f2bf(s0[2 * i + 1]));
                pd1[i] = pack2(f2bf(s1[2 * i]), f2bf(s1[2 * i + 1]));
                po0[i] = __shfl_xor(pd0[i], 32, 64);
                po1[i] = __shfl_xor(pd1[i], 32, 64);
            }
            // B-frag for k-step ks (kv = ks*16 + 8*hi + j):
            //   ks&1==0: hi ? [po2,po3,pd2,pd3] : [pd0,pd1,po0,po1]
            //   ks&1==1: hi ? [po6,po7,pd6,pd7] : [pd4,pd5,po4,po5]
            bf16x8_t pf[4];
#pragma unroll
            for (int ks = 0; ks < 4; ++ks) {
                const u32* pd = (ks < 2) ? pd0 : pd1;
                const u32* po = (ks < 2) ? po0 : po1;
                int base = (ks & 1) * 4;
                union { u32 u[4]; bf16x8_t v; } f;
                f.u[0] = hi ? po[base + 2] : pd[base + 0];
                f.u[1] = hi ? po[base + 3] : pd[base + 1];
                f.u[2] = hi ? pd[base + 2] : po[base + 0];
                f.u[3] = hi ? pd[base + 3] : po[base + 1];
                pf[ks] = f.v;
            }
            // ---- O^T += V^T P: A=V^T[d][kv], B=P[kv][q] ----
            __builtin_amdgcn_s_setprio(1);
#pragma unroll
            for (int dt = 0; dt < 4; ++dt) {
                int dl = dt * 32 + col;
#pragma unroll
                for (int ks = 0; ks < 4; ++ks) {
                    bf16x8_t vf = *(const bf16x8_t*)
                        (&Vt[cur][dl * 64 + (((2 * ks + hi) ^ l7) * 8)]);
                    o[dt] = __builtin_amdgcn_mfma_f32_32x32x16_bf16(vf, pf[ks], o[dt], 0, 0, 0);
                }
            }
            __builtin_amdgcn_s_setprio(0);
        }
        __syncthreads();                // drains prefetch (hidden) + LDS reuse
    }
#undef STAGE

    // ---- epilogue: combine l halves, O^T -> [q][d] via LDS, 16B stores ----
    float ltot = lrow + __shfl_xor(lrow, 32, 64);
    float inv  = 1.0f / ltot;
    u16* Tr = &Kt[0][0] + w * 4096;     // per-wave 32 q x 128 d region (8 KB)
    // o[dt][4g+j] holds d = dt*32 + 8g + 4hi + j (j=0..3 consecutive) -> b64
#pragma unroll
    for (int dt = 0; dt < 4; ++dt)
#pragma unroll
        for (int g = 0; g < 4; ++g) {
            int slot = ((dt << 2) | g) ^ (col & 7);     // bank swizzle (3-bit)
            u32 lo  = pack2(f2bf(o[dt][4 * g + 0] * inv), f2bf(o[dt][4 * g + 1] * inv));
            u32 hi2 = pack2(f2bf(o[dt][4 * g + 2] * inv), f2bf(o[dt][4 * g + 3] * inv));
            *(uint2*)(Tr + col * 128 + slot * 8 + 4 * hi) = make_uint2(lo, hi2);
        }
    // same-wave write->read (disjoint per-wave regions; in-order LDS pipe)
    size_t rowbase = (size_t)(b * T_ + qw0);
#pragma unroll
    for (int p = 0; p < 8; ++p) {
        int ql   = p * 4 + (lane >> 4);
        int slot = lane & 15;
        int dl   = (slot ^ (ql & 7)) * 8;
        u32x4_t v = *(const u32x4_t*)(Tr + ql * 128 + slot * 8);
        *(u32x4_t*)(attout + (rowbase + ql) * 2048 + h * HD_ + dl) = v;
    }
}

// ---------------------------------------------------------------------------
// launch
// ---------------------------------------------------------------------------
extern "C" void kernel_launch(void* const* d_in, const int* in_sizes, int n_in,
                              void* d_out, int out_size, void* d_ws, size_t ws_size,
                              hipStream_t stream) {
    const float* x    = (const float*)d_in[0];
    const float* Wq   = (const float*)d_in[1];
    const float* Wk   = (const float*)d_in[2];
    const float* Wv   = (const float*)d_in[3];
    const float* Wo   = (const float*)d_in[4];
    const float* qw   = (const float*)d_in[5];
    const float* kw   = (const float*)d_in[6];
    const float* sinT = (const float*)d_in[7];
    const float* cosT = (const float*)d_in[8];
    float* out = (float*)d_out;

    u16*  x_bf   = (u16*)d_ws;                                   // [4096][2048]
    u16*  wqkv_t = x_bf   + (size_t)M_ * D_;                     // [4096][2048]
    u16*  wo_t   = wqkv_t + (size_t)4096 * 2048;                 // [2048][2048]
    float* c_qkv = (float*)(wo_t + (size_t)2048 * 2048);         // [4096][4096]
    u16*  q_bf   = (u16*)(c_qkv + (size_t)M_ * NQKV_);           // [2][16][2048][128]
    u16*  k_bf   = q_bf + (size_t)B_ * H_  * T_ * HD_;           // [2][8][2048][128]
    u16*  v_bf   = k_bf + (size_t)B_ * KH_ * T_ * HD_;           // [2][8][2048][128]
    u16*  v_t    = v_bf + (size_t)B_ * KH_ * T_ * HD_;           // [2][8][128][2048]
    u16*  att_bf = v_t  + (size_t)B_ * KH_ * T_ * HD_;           // [4096][2048]

    cast_x_kernel<<<(M_ * D_) / 1024, 256, 0, stream>>>(x, x_bf);
    tcast_kernel<<<dim3(32, 32), 256, 0, stream>>>(Wq, wqkv_t, 2048);
    tcast_kernel<<<dim3(32, 16), 256, 0, stream>>>(Wk, wqkv_t + (size_t)2048 * 2048, 1024);
    tcast_kernel<<<dim3(32, 16), 256, 0, stream>>>(Wv, wqkv_t + (size_t)3072 * 2048, 1024);
    tcast_kernel<<<dim3(32, 32), 256, 0, stream>>>(Wo, wo_t, 2048);

    gemm_kernel<<<dim3(32, 32), 256, 0, stream>>>(x_bf, wqkv_t, c_qkv, 4096);
    normrope_kernel<<<(M_ * 32) / 4, 256, 0, stream>>>(c_qkv, qw, kw, sinT, cosT,
                                                       q_bf, k_bf, v_bf);
    vtrans_kernel<<<dim3(32, 2, 16), 256, 0, stream>>>(v_bf, v_t);
    attn_kernel<<<dim3(16, 16, 2), 256, 0, stream>>>(q_bf, k_bf, v_t, att_bf);
    gemm_kernel<<<dim3(32, 16), 256, 0, stream>>>(att_bf, wo_t, out, 2048);
}

// Round 6
// 397.331 us; speedup vs baseline: 1.2371x; 1.0446x over previous
//
#include <hip/hip_runtime.h>
#include <stdint.h>

// ---------------------------------------------------------------------------
// Qwen attention block: x@Wqkv -> RMSnorm -> RoPE -> causal GQA flash attn ->
// @Wo.  B=2 T=2048 D=2048 H=16 KH=8 Hd=128.  bf16 MFMA, f32 accum.
// R6: GEMMs upgraded to the 256x256 8-phase template (T2 LDS swizzle +
// T3/T4 counted-vmcnt phase pipeline + T5 setprio).  attn unchanged from R5.
// ---------------------------------------------------------------------------

#define B_ 2
#define T_ 2048
#define D_ 2048
#define H_ 16
#define KH_ 8
#define HD_ 128
#define M_ (B_*T_)          // 4096 tokens
#define NQKV_ 4096          // q(2048) | k(1024) | v(1024)
#define QK_SCALE_LOG2E 0.1275174337f

typedef unsigned short u16;
typedef unsigned int   u32;
typedef __attribute__((ext_vector_type(8)))  __bf16 bf16x8_t;
typedef __attribute__((ext_vector_type(4)))  float  f32x4_t;
typedef __attribute__((ext_vector_type(16))) float  f32x16_t;
typedef __attribute__((ext_vector_type(4)))  u32    u32x4_t;

__device__ __forceinline__ u16 f2bf(float f) {          // RNE f32 -> bf16
    u32 x = __float_as_uint(f);
    return (u16)((x + 0x7fffu + ((x >> 16) & 1u)) >> 16);
}
__device__ __forceinline__ u32 pack2(u16 a, u16 b) { return (u32)a | ((u32)b << 16); }

// async global->LDS, 16B per lane.  LDS dest is wave-uniform base; lane i's
// 16B lands at base + i*16.
__device__ __forceinline__ void gload16(const void* g, void* l) {
    __builtin_amdgcn_global_load_lds(
        (__attribute__((address_space(1))) const void*)(unsigned long long)g,
        (__attribute__((address_space(3))) void*)(u32)(unsigned long long)l,
        16, 0, 0);
}

// ---------------------------------------------------------------------------
// 1) cast x (f32) -> bf16
// ---------------------------------------------------------------------------
__global__ void cast_x_kernel(const float* __restrict__ in, u16* __restrict__ out) {
    int i = (blockIdx.x * 256 + threadIdx.x) * 4;
    float4 v = *(const float4*)(in + i);
    u32 lo = pack2(f2bf(v.x), f2bf(v.y));
    u32 hi = pack2(f2bf(v.z), f2bf(v.w));
    *(uint2*)(out + i) = make_uint2(lo, hi);
}

// ---------------------------------------------------------------------------
// 2) transpose+cast weight: in f32 [2048][ncols] -> out bf16 [ncols][2048]
// ---------------------------------------------------------------------------
__global__ void tcast_kernel(const float* __restrict__ in, u16* __restrict__ out,
                             int ncols) {
    __shared__ u16 tile[64][65];
    int k0 = blockIdx.x * 64;
    int n0 = blockIdx.y * 64;
    int tid = threadIdx.x;
#pragma unroll
    for (int i = 0; i < 8; ++i) {
        int idx = tid + i * 256;
        int r = idx >> 5, c2 = idx & 31;
        float2 v = *(const float2*)(in + (size_t)(k0 + r) * ncols + n0 + 2 * c2);
        tile[r][2 * c2]     = f2bf(v.x);
        tile[r][2 * c2 + 1] = f2bf(v.y);
    }
    __syncthreads();
#pragma unroll
    for (int i = 0; i < 8; ++i) {
        int idx = tid + i * 256;
        int rn = idx >> 5, c2 = idx & 31;
        *(u32*)(out + (size_t)(n0 + rn) * 2048 + k0 + 2 * c2) =
            pack2(tile[2 * c2][rn], tile[2 * c2 + 1][rn]);
    }
}

// ---------------------------------------------------------------------------
// 3) GEMM, 256x256 tile, BK=64, 8 waves (2M x 4N), 8-phase counted-vmcnt
//    pipeline.  C[M][N] f32 = A[M][2048] bf16 @ Bt[N][2048] bf16.
//    LDS: As/Bs [2][256][8 slots of 8 elems], slot swizzle phys = slot^(row&7)
//    applied on BOTH stage-source and ds_read (rule #21).
//    Per K-tile: 4 phases, each {ds_read quad || issue 1 half-tile -> barrier
//    -> lgkmcnt(0) -> 16 MFMA -> barrier}; vmcnt(4) once per tile (ph3).
//    Issue schedule: ph0/ph1: A-lo/A-hi(kt+1) [other buf]; ph2/ph3:
//    B-lo/B-hi(kt+2) [same buf, regions whose reads ended at ph1].
// ---------------------------------------------------------------------------
#define NKT 32              // K = 2048 / BK = 64

__global__ void __launch_bounds__(512, 2)
gemm8p_kernel(const u16* __restrict__ A, const u16* __restrict__ Bt,
              float* __restrict__ C, int N) {
    __shared__ u16 As[2][256 * 64];
    __shared__ u16 Bs[2][256 * 64];
    const int tid  = threadIdx.x;
    const int lane = tid & 63;
    const int w    = tid >> 6;          // 0..7
    const int wm   = w >> 2;            // 0..1 -> m rows wm*128..+127
    const int wn   = w & 3;             // 0..3 -> n cols wn*64..+63
    const int m0 = blockIdx.x * 256;
    const int n0 = blockIdx.y * 256;
    const int fr = lane & 15;
    const int kg = lane >> 4;

    const u16* Ag = A  + (size_t)m0 * 2048;
    const u16* Bg = Bt + (size_t)n0 * 2048;

    // stage one half-tile (128 rows x 64 cols, 16KB): 2 gload16/thread.
    // chunk c = i*512 + w*64 + lane; row = c>>3 (+h*128), phys slot = c&7;
    // source slot = phys ^ (row&7)  (involution; read applies same XOR).
#define STG(gbase, lbase, h, kt_)                                              \
    do {                                                                       \
        int _k0 = (kt_) * 64;                                                  \
        _Pragma("unroll")                                                      \
        for (int _i = 0; _i < 2; ++_i) {                                       \
            int _r  = _i * 64 + w * 8 + (lane >> 3);                           \
            int _sl = (lane & 7) ^ (_r & 7);                                   \
            gload16((gbase) + (size_t)((h) * 128 + _r) * 2048 + _k0 + _sl * 8, \
                    (lbase) + (h) * 8192 + (_i * 512 + w * 64) * 8);           \
        }                                                                      \
    } while (0)

    bf16x8_t afr[4][2];          // A quad: 4 mfrags x 2 ksteps
    bf16x8_t bfr[2][2][2];       // B: [qn][nf][ks], both qn halves persist
    f32x4_t  acc[8][4];
#pragma unroll
    for (int i = 0; i < 8; ++i)
#pragma unroll
        for (int j = 0; j < 4; ++j)
#pragma unroll
            for (int e = 0; e < 4; ++e) acc[i][j][e] = 0.0f;

#define RDA(qm)                                                                \
    _Pragma("unroll")                                                          \
    for (int _mf = 0; _mf < 4; ++_mf)                                          \
        _Pragma("unroll")                                                      \
        for (int _ks = 0; _ks < 2; ++_ks) {                                    \
            int _row  = wm * 128 + ((qm) * 4 + _mf) * 16 + fr;                 \
            int _phys = (_ks * 4 + kg) ^ (_row & 7);                           \
            afr[_mf][_ks] = *(const bf16x8_t*)(Asc + _row * 64 + _phys * 8);   \
        }
#define RDB(qn)                                                                \
    _Pragma("unroll")                                                          \
    for (int _nf = 0; _nf < 2; ++_nf)                                          \
        _Pragma("unroll")                                                      \
        for (int _ks = 0; _ks < 2; ++_ks) {                                    \
            int _row  = wn * 64 + ((qn) * 2 + _nf) * 16 + fr;                  \
            int _phys = (_ks * 4 + kg) ^ (_row & 7);                           \
            bfr[qn][_nf][_ks] = *(const bf16x8_t*)(Bsc + _row * 64 + _phys * 8);\
        }
#define MM(qm, qn)                                                             \
    _Pragma("unroll")                                                          \
    for (int _mf = 0; _mf < 4; ++_mf)                                          \
        _Pragma("unroll")                                                      \
        for (int _nf = 0; _nf < 2; ++_nf)                                      \
            _Pragma("unroll")                                                  \
            for (int _ks = 0; _ks < 2; ++_ks)                                  \
                acc[(qm) * 4 + _mf][(qn) * 2 + _nf] =                          \
                    __builtin_amdgcn_mfma_f32_16x16x32_bf16(                   \
                        afr[_mf][_ks], bfr[qn][_nf][_ks],                      \
                        acc[(qm) * 4 + _mf][(qn) * 2 + _nf], 0, 0, 0);

#define SBAR __builtin_amdgcn_sched_barrier(0)
#define PH_MID                                                                 \
    SBAR; __builtin_amdgcn_s_barrier();                                        \
    asm volatile("s_waitcnt lgkmcnt(0)" ::: "memory"); SBAR;                   \
    __builtin_amdgcn_s_setprio(1)
#define PH_END                                                                 \
    __builtin_amdgcn_s_setprio(0); SBAR;                                       \
    __builtin_amdgcn_s_barrier(); SBAR

    // ---- prologue: tile0 (4 halves) + tile1 B halves; wait tile0 ----
    STG(Ag, &As[0][0], 0, 0);
    STG(Ag, &As[0][0], 1, 0);
    STG(Bg, &Bs[0][0], 0, 0);
    STG(Bg, &Bs[0][0], 1, 0);
    STG(Bg, &Bs[1][0], 0, 1);
    STG(Bg, &Bs[1][0], 1, 1);
    asm volatile("s_waitcnt vmcnt(4)" ::: "memory");
    SBAR;
    __builtin_amdgcn_s_barrier();
    SBAR;

    for (int kt = 0; kt < NKT; ++kt) {
        const int cur = kt & 1;
        const u16* Asc = &As[cur][0];
        const u16* Bsc = &Bs[cur][0];
        u16* Aso = &As[cur ^ 1][0];
        u16* Bsw = &Bs[cur][0];
        // ---- phase 0: read A(qm0)+B(qn0); issue A-lo(kt+1) ----
        RDA(0); RDB(0);
        if (kt + 1 < NKT) STG(Ag, Aso, 0, kt + 1);
        PH_MID; MM(0, 0); PH_END;
        // ---- phase 1: read B(qn1); issue A-hi(kt+1) ----
        RDB(1);
        if (kt + 1 < NKT) STG(Ag, Aso, 1, kt + 1);
        PH_MID; MM(0, 1); PH_END;
        // ---- phase 2: read A(qm1); issue B-lo(kt+2) ----
        RDA(1);
        if (kt + 2 < NKT) STG(Bg, Bsw, 0, kt + 2);
        PH_MID; MM(1, 0); PH_END;
        // ---- phase 3: issue B-hi(kt+2); counted vmcnt at tile boundary ----
        if (kt + 2 < NKT) STG(Bg, Bsw, 1, kt + 2);
        SBAR; __builtin_amdgcn_s_barrier(); SBAR;
        __builtin_amdgcn_s_setprio(1);
        MM(1, 1);
        __builtin_amdgcn_s_setprio(0); SBAR;
        if (kt < NKT - 2) asm volatile("s_waitcnt vmcnt(4)" ::: "memory");
        else              asm volatile("s_waitcnt vmcnt(0)" ::: "memory");
        SBAR;
        __builtin_amdgcn_s_barrier();
        SBAR;
    }
#undef STG
#undef RDA
#undef RDB
#undef MM
#undef PH_MID
#undef PH_END

    // ---- epilogue: C/D layout col=lane&15 (n), row=kg*4+j (m) ----
#pragma unroll
    for (int mf = 0; mf < 8; ++mf)
#pragma unroll
        for (int nf = 0; nf < 4; ++nf) {
            int colx  = n0 + wn * 64 + nf * 16 + fr;
            int rbase = m0 + wm * 128 + mf * 16 + kg * 4;
#pragma unroll
            for (int j = 0; j < 4; ++j)
                C[(size_t)(rbase + j) * N + colx] = acc[mf][nf][j];
        }
}

// ---------------------------------------------------------------------------
// 4) RMSnorm + RoPE.  One wave per (token, head-row).
// ---------------------------------------------------------------------------
__global__ void __launch_bounds__(256)
normrope_kernel(const float* __restrict__ Cqkv,
                const float* __restrict__ qw, const float* __restrict__ kw,
                const float* __restrict__ sinT, const float* __restrict__ cosT,
                u16* __restrict__ qbf, u16* __restrict__ kbf, u16* __restrict__ vbf) {
    int lane = threadIdx.x & 63;
    int w    = threadIdx.x >> 6;
    int rid  = blockIdx.x * 4 + w;
    int m   = rid >> 5;
    int sub = rid & 31;
    int b = m >> 11, t = m & (T_ - 1);

    if (sub >= 24) {                                     // v: plain cast
        int kh = sub - 24;
        float2 x = *(const float2*)(Cqkv + (size_t)m * NQKV_ + 3072 + kh * HD_ + 2 * lane);
        *(u32*)(vbf + ((size_t)(b * KH_ + kh) * T_ + t) * HD_ + 2 * lane) =
            pack2(f2bf(x.x), f2bf(x.y));
        return;
    }
    bool isq = sub < 16;
    int  hh  = isq ? sub : sub - 16;
    int  colbase = isq ? hh * HD_ : 2048 + hh * HD_;
    float2 x = *(const float2*)(Cqkv + (size_t)m * NQKV_ + colbase + 2 * lane);
    float ss = x.x * x.x + x.y * x.y;
#pragma unroll
    for (int sh = 1; sh < 64; sh <<= 1) ss += __shfl_xor(ss, sh, 64);
    float scale = rsqrtf(ss * (1.0f / 128.0f) + 1e-6f);
    const float* wp = isq ? qw : kw;
    float2 wv = *(const float2*)(wp + 2 * lane);
    float y1 = x.x * scale * wv.x;
    float y2 = x.y * scale * wv.y;
    float c = cosT[t * 64 + lane], s = sinT[t * 64 + lane];
    float oa = y1 * c - y2 * s;
    float ob = y1 * s + y2 * c;
    if (isq) { oa *= QK_SCALE_LOG2E; ob *= QK_SCALE_LOG2E; }
    u16* outp = isq ? (qbf + ((size_t)(b * H_  + hh) * T_ + t) * HD_)
                    : (kbf + ((size_t)(b * KH_ + hh) * T_ + t) * HD_);
    outp[lane]      = f2bf(oa);
    outp[64 + lane] = f2bf(ob);
}

// ---------------------------------------------------------------------------
// 5) V transpose: [BH][T][128] -> [BH][128][T]
// ---------------------------------------------------------------------------
__global__ void vtrans_kernel(const u16* __restrict__ in, u16* __restrict__ out) {
    __shared__ u16 tile[64][65];
    int t0 = blockIdx.x * 64;
    int d0 = blockIdx.y * 64;
    size_t bi = (size_t)blockIdx.z * T_ * HD_;
    size_t bo = (size_t)blockIdx.z * HD_ * T_;
    int tid = threadIdx.x;
#pragma unroll
    for (int i = 0; i < 8; ++i) {
        int idx = tid + i * 256;
        int r = idx >> 5, c2 = idx & 31;
        u32 v = *(const u32*)(in + bi + (size_t)(t0 + r) * HD_ + d0 + 2 * c2);
        tile[r][2 * c2]     = (u16)(v & 0xffffu);
        tile[r][2 * c2 + 1] = (u16)(v >> 16);
    }
    __syncthreads();
#pragma unroll
    for (int i = 0; i < 8; ++i) {
        int idx = tid + i * 256;
        int rd = idx >> 5, c2 = idx & 31;
        *(u32*)(out + bo + (size_t)(d0 + rd) * T_ + t0 + 2 * c2) =
            pack2(tile[2 * c2][rd], tile[2 * c2 + 1][rd]);
    }
}

// ---------------------------------------------------------------------------
// 6) Causal GQA flash attention (unchanged from R5).
// ---------------------------------------------------------------------------
__global__ void __launch_bounds__(256, 2)
attn_kernel(const u16* __restrict__ qg, const u16* __restrict__ kgl,
            const u16* __restrict__ vtg, u16* __restrict__ attout) {
    __shared__ u16 Kt[2][64 * 128];     // 16 KB each: rows = kv, 16 slots of 16B
    __shared__ u16 Vt[2][128 * 64];     // 16 KB each: rows = d,   8 slots of 16B

    const int tid = threadIdx.x, lane = tid & 63, w = tid >> 6;
    const int qb = (int)gridDim.x - 1 - (int)blockIdx.x;   // big blocks first
    const int h = blockIdx.y, b = blockIdx.z;
    const int kh = h >> 1;                       // GQA rep=2
    const int q0 = qb * 128;
    const int col = lane & 31;                   // q index within wave tile
    const int hi  = lane >> 5;                   // half selector
    const int l7  = lane & 7;
    const int l15 = lane & 15;
    const int qw0 = q0 + w * 32;
    const int qlane = qw0 + col;                 // this lane's q row

    const u16* qbase = qg  + ((size_t)(b * H_  + h ) * T_) * HD_;
    const u16* kbase = kgl + ((size_t)(b * KH_ + kh) * T_) * HD_;
    const u16* vbase = vtg + ((size_t)(b * KH_ + kh) * HD_) * T_;

    // Q as B-operand fragments: qf[s] = Q[qlane][s*16 + 8*hi + j], j=0..7
    bf16x8_t qf[8];
#pragma unroll
    for (int s = 0; s < 8; ++s)
        qf[s] = *(const bf16x8_t*)(qbase + (size_t)qlane * HD_ + s * 16 + hi * 8);

    // staging lane roles
    const int krl = lane >> 4, kcl = lane & 15;   // K chunk: 4 rows x 16 slots
    const int vrl = lane >> 3, vcl = lane & 7;    // V chunk: 8 rows x 8 slots

    f32x16_t o[4];                               // O^T: d = dt*32+crow, q = col
#pragma unroll
    for (int dt = 0; dt < 4; ++dt)
#pragma unroll
        for (int r = 0; r < 16; ++r) o[dt][r] = 0.0f;
    float mrow = -1e30f, lrow = 0.0f;            // lrow = PARTIAL (own 32 kv/tile)

    const int nt = 2 * (qb + 1);

#define STAGE(buf, tt)                                                          \
    do {                                                                        \
        int kv0s = (tt) * 64;                                                   \
        _Pragma("unroll")                                                       \
        for (int cc = 0; cc < 4; ++cc) {                                        \
            int c = w * 4 + cc;                                                 \
            int r = c * 4 + krl;                                                \
            gload16(kbase + (size_t)(kv0s + r) * HD_ + (kcl ^ (r & 15)) * 8,    \
                    &Kt[buf][c * 512]);                                         \
            int rv = c * 8 + vrl;                                               \
            gload16(vbase + (size_t)rv * T_ + kv0s + (vcl ^ (rv & 7)) * 8,      \
                    &Vt[buf][c * 512]);                                         \
        }                                                                       \
    } while (0)

    STAGE(0, 0);
    __syncthreads();                    // tile 0 staged

    for (int t = 0; t < nt; ++t) {
        const int cur = t & 1;
        const int kv0 = t * 64;
        if (t + 1 < nt) STAGE(cur ^ 1, t + 1);   // issue-early prefetch

        if (kv0 <= qw0 + 31) {          // wave-uniform diagonal skip
            // ---- S^T = K Q^T: A=K[kv][d], B=Q[d][q] (pre-scaled log2e) ----
            f32x16_t s0, s1;
#pragma unroll
            for (int r = 0; r < 16; ++r) { s0[r] = 0.0f; s1[r] = 0.0f; }
            __builtin_amdgcn_s_setprio(1);
#pragma unroll
            for (int ss = 0; ss < 8; ++ss) {
                bf16x8_t kf0 = *(const bf16x8_t*)
                    (&Kt[cur][col * 128 + (((2 * ss + hi) ^ l15) * 8)]);
                s0 = __builtin_amdgcn_mfma_f32_32x32x16_bf16(kf0, qf[ss], s0, 0, 0, 0);
                bf16x8_t kf1 = *(const bf16x8_t*)
                    (&Kt[cur][(32 + col) * 128 + (((2 * ss + hi) ^ l15) * 8)]);
                s1 = __builtin_amdgcn_mfma_f32_32x32x16_bf16(kf1, qf[ss], s1, 0, 0, 0);
            }
            __builtin_amdgcn_s_setprio(0);
            // ---- causal mask (tiles overlapping any of this wave's rows) ----
            if (kv0 + 63 > qw0) {
#pragma unroll
                for (int r = 0; r < 16; ++r) {
                    int cr = (r & 3) + 8 * (r >> 2) + 4 * hi;
                    if (kv0 + cr      > qlane) s0[r] = -1e30f;
                    if (kv0 + 32 + cr > qlane) s1[r] = -1e30f;
                }
            }
            // ---- softmax (lane-local; one cross-half combine for max) ----
            float tmax = s0[0];
#pragma unroll
            for (int r = 1; r < 16; ++r) tmax = fmaxf(tmax, s0[r]);
#pragma unroll
            for (int r = 0; r < 16; ++r) tmax = fmaxf(tmax, s1[r]);
            tmax = fmaxf(tmax, __shfl_xor(tmax, 32, 64));
            float mnew = fmaxf(mrow, tmax);
            float corr = exp2f(mrow - mnew);
            mrow = mnew;
            float ps = 0.0f;
#pragma unroll
            for (int r = 0; r < 16; ++r) {
                s0[r] = exp2f(s0[r] - mrow); ps += s0[r];
                s1[r] = exp2f(s1[r] - mrow); ps += s1[r];
            }
            lrow = lrow * corr + ps;            // stays partial per half-lane
#pragma unroll
            for (int dt = 0; dt < 4; ++dt)
#pragma unroll
                for (int r = 0; r < 16; ++r) o[dt][r] *= corr;
            // ---- P -> bf16 pairs, redistribute to B-operand layout ----
            u32 pd0[8], pd1[8], po0[8], po1[8];
#pragma unroll
            for (int i = 0; i < 8; ++i) {
                pd0[i] = pack2(f2bf(s0[2 * i]), f2bf(s0[2 * i + 1]));
                pd1[i] = pack2(f2bf(s1[2 * i]), f2bf(s1[2 * i + 1]));
                po0[i] = __shfl_xor(pd0[i], 32, 64);
                po1[i] = __shfl_xor(pd1[i], 32, 64);
            }
            bf16x8_t pf[4];
#pragma unroll
            for (int ks = 0; ks < 4; ++ks) {
                const u32* pd = (ks < 2) ? pd0 : pd1;
                const u32* po = (ks < 2) ? po0 : po1;
                int base = (ks & 1) * 4;
                union { u32 u[4]; bf16x8_t v; } f;
                f.u[0] = hi ? po[base + 2] : pd[base + 0];
                f.u[1] = hi ? po[base + 3] : pd[base + 1];
                f.u[2] = hi ? pd[base + 2] : po[base + 0];
                f.u[3] = hi ? pd[base + 3] : po[base + 1];
                pf[ks] = f.v;
            }
            // ---- O^T += V^T P: A=V^T[d][kv], B=P[kv][q] ----
            __builtin_amdgcn_s_setprio(1);
#pragma unroll
            for (int dt = 0; dt < 4; ++dt) {
                int dl = dt * 32 + col;
#pragma unroll
                for (int ks = 0; ks < 4; ++ks) {
                    bf16x8_t vf = *(const bf16x8_t*)
                        (&Vt[cur][dl * 64 + (((2 * ks + hi) ^ l7) * 8)]);
                    o[dt] = __builtin_amdgcn_mfma_f32_32x32x16_bf16(vf, pf[ks], o[dt], 0, 0, 0);
                }
            }
            __builtin_amdgcn_s_setprio(0);
        }
        __syncthreads();                // drains prefetch (hidden) + LDS reuse
    }
#undef STAGE

    // ---- epilogue: combine l halves, O^T -> [q][d] via LDS, 16B stores ----
    float ltot = lrow + __shfl_xor(lrow, 32, 64);
    float inv  = 1.0f / ltot;
    u16* Tr = &Kt[0][0] + w * 4096;     // per-wave 32 q x 128 d region (8 KB)
#pragma unroll
    for (int dt = 0; dt < 4; ++dt)
#pragma unroll
        for (int g = 0; g < 4; ++g) {
            int slot = ((dt << 2) | g) ^ (col & 7);     // bank swizzle (3-bit)
            u32 lo  = pack2(f2bf(o[dt][4 * g + 0] * inv), f2bf(o[dt][4 * g + 1] * inv));
            u32 hi2 = pack2(f2bf(o[dt][4 * g + 2] * inv), f2bf(o[dt][4 * g + 3] * inv));
            *(uint2*)(Tr + col * 128 + slot * 8 + 4 * hi) = make_uint2(lo, hi2);
        }
    size_t rowbase = (size_t)(b * T_ + qw0);
#pragma unroll
    for (int p = 0; p < 8; ++p) {
        int ql   = p * 4 + (lane >> 4);
        int slot = lane & 15;
        int dl   = (slot ^ (ql & 7)) * 8;
        u32x4_t v = *(const u32x4_t*)(Tr + ql * 128 + slot * 8);
        *(u32x4_t*)(attout + (rowbase + ql) * 2048 + h * HD_ + dl) = v;
    }
}

// ---------------------------------------------------------------------------
// launch
// ---------------------------------------------------------------------------
extern "C" void kernel_launch(void* const* d_in, const int* in_sizes, int n_in,
                              void* d_out, int out_size, void* d_ws, size_t ws_size,
                              hipStream_t stream) {
    const float* x    = (const float*)d_in[0];
    const float* Wq   = (const float*)d_in[1];
    const float* Wk   = (const float*)d_in[2];
    const float* Wv   = (const float*)d_in[3];
    const float* Wo   = (const float*)d_in[4];
    const float* qw   = (const float*)d_in[5];
    const float* kw   = (const float*)d_in[6];
    const float* sinT = (const float*)d_in[7];
    const float* cosT = (const float*)d_in[8];
    float* out = (float*)d_out;

    u16*  x_bf   = (u16*)d_ws;                                   // [4096][2048]
    u16*  wqkv_t = x_bf   + (size_t)M_ * D_;                     // [4096][2048]
    u16*  wo_t   = wqkv_t + (size_t)4096 * 2048;                 // [2048][2048]
    float* c_qkv = (float*)(wo_t + (size_t)2048 * 2048);         // [4096][4096]
    u16*  q_bf   = (u16*)(c_qkv + (size_t)M_ * NQKV_);           // [2][16][2048][128]
    u16*  k_bf   = q_bf + (size_t)B_ * H_  * T_ * HD_;           // [2][8][2048][128]
    u16*  v_bf   = k_bf + (size_t)B_ * KH_ * T_ * HD_;           // [2][8][2048][128]
    u16*  v_t    = v_bf + (size_t)B_ * KH_ * T_ * HD_;           // [2][8][128][2048]
    u16*  att_bf = v_t  + (size_t)B_ * KH_ * T_ * HD_;           // [4096][2048]

    cast_x_kernel<<<(M_ * D_) / 1024, 256, 0, stream>>>(x, x_bf);
    tcast_kernel<<<dim3(32, 32), 256, 0, stream>>>(Wq, wqkv_t, 2048);
    tcast_kernel<<<dim3(32, 16), 256, 0, stream>>>(Wk, wqkv_t + (size_t)2048 * 2048, 1024);
    tcast_kernel<<<dim3(32, 16), 256, 0, stream>>>(Wv, wqkv_t + (size_t)3072 * 2048, 1024);
    tcast_kernel<<<dim3(32, 32), 256, 0, stream>>>(Wo, wo_t, 2048);

    gemm8p_kernel<<<dim3(16, 16), 512, 0, stream>>>(x_bf, wqkv_t, c_qkv, 4096);
    normrope_kernel<<<(M_ * 32) / 4, 256, 0, stream>>>(c_qkv, qw, kw, sinT, cosT,
                                                       q_bf, k_bf, v_bf);
    vtrans_kernel<<<dim3(32, 2, 16), 256, 0, stream>>>(v_bf, v_t);
    attn_kernel<<<dim3(16, 16, 2), 256, 0, stream>>>(q_bf, k_bf, v_t, att_bf);
    gemm8p_kernel<<<dim3(16, 8), 512, 0, stream>>>(att_bf, wo_t, out, 2048);
}